// Round 9
// baseline (44.296 us; speedup 1.0000x reference)
//
#include <hip/hip_runtime.h>

// DIAGNOSTIC build of R7: tile loop executed REP=3 times (identical values,
// out overwritten each rep -> correct output), with opaque asm on x0/x1/x2
// so the compiler cannot CSE the compute across reps. Purpose: (a) surface
// our kernel above the 40us harness fills in rocprof top-5, (b) separate
// per-wave fixed cost from loop cost via dur(3x) vs dur(1x).

#define NPTS  2097152
#define BLOCK 256
#define TILES 4
#define NBLK  (NPTS / (BLOCK * TILES))   // 2048
#define REP   3

typedef __bf16 bf16x8 __attribute__((ext_vector_type(8)));
typedef float  f32x4  __attribute__((ext_vector_type(4)));

__global__ __launch_bounds__(BLOCK, 8) void nerf_mfma7_diag(
    const float* __restrict__ x,
    const float* __restrict__ W1,
    const float* __restrict__ b1,
    const float* __restrict__ W2,
    const float* __restrict__ b2,
    float* __restrict__ out)
{
    const int tid  = threadIdx.x;
    const int wave = tid >> 6;
    const int lane = tid & 63;
    const int g    = lane >> 4;
    const int c    = lane & 15;

    const float INV2PI = 0.15915494309189535f;
    float Fg = 1.0f;
    Fg = (g == 1) ? 10.079368f : Fg;
    Fg = (g == 2) ? 101.59367f : Fg;
    Fg = (g == 3) ? 1024.0f    : Fg;
    Fg *= INV2PI;

    bf16x8 afrag[2];
    #pragma unroll
    for (int mt = 0; mt < 2; ++mt) {
        const int j = mt * 16 + c;
        #pragma unroll
        for (int i = 0; i < 3; ++i)
            afrag[mt][i] = (__bf16)W1[(3 + 6 * g + i) * 32 + j];
        #pragma unroll
        for (int i = 3; i < 6; ++i)
            afrag[mt][i] = (__bf16)W1[(6 + 6 * g + (i - 3)) * 32 + j];
        afrag[mt][6] = (__bf16)((g < 3) ? W1[g * 32 + j] : b1[j]);
        afrag[mt][7] = (__bf16)0.0f;
    }

    bf16x8 a2;
    #pragma unroll
    for (int i = 0; i < 4; ++i) {
        a2[i]     = (__bf16)W2[4 * g + i];
        a2[4 + i] = (__bf16)W2[16 + 4 * g + i];
    }
    const float bias2 = b2[0];

    const int tbase = blockIdx.x * (4 * TILES) + wave * TILES;

    #pragma unroll 1
    for (int rep = 0; rep < REP; ++rep) {
        #pragma unroll
        for (int t = 0; t < TILES; ++t) {
            const float3* xb3 = (const float3*)(x + (size_t)(tbase + t) * 192);
            float3 P[4];
            #pragma unroll
            for (int nt = 0; nt < 4; ++nt) P[nt] = xb3[16 * nt + c];

            float p[4];
            #pragma unroll
            for (int nt = 0; nt < 4; ++nt) {
                float x0 = P[nt].x, x1 = P[nt].y, x2 = P[nt].z;
                // opaque: forces per-rep recompute of everything downstream
                asm volatile("" : "+v"(x0), "+v"(x1), "+v"(x2));

                const float a0  = __builtin_amdgcn_fractf(x0 * Fg);
                const float a1  = __builtin_amdgcn_fractf(x1 * Fg);
                const float a2f = __builtin_amdgcn_fractf(x2 * Fg);
                float extra = x0;
                extra = (g == 1) ? x1 : extra;
                extra = (g == 2) ? x2 : extra;
                extra = (g == 3) ? 1.0f : extra;

                bf16x8 bf;
                bf[0] = (__bf16)__builtin_amdgcn_sinf(a0);
                bf[1] = (__bf16)__builtin_amdgcn_sinf(a1);
                bf[2] = (__bf16)__builtin_amdgcn_sinf(a2f);
                bf[3] = (__bf16)__builtin_amdgcn_cosf(a0);
                bf[4] = (__bf16)__builtin_amdgcn_cosf(a1);
                bf[5] = (__bf16)__builtin_amdgcn_cosf(a2f);
                bf[6] = (__bf16)extra;
                bf[7] = (__bf16)0.0f;

                f32x4 acc0 = {0.f, 0.f, 0.f, 0.f};
                f32x4 acc1 = {0.f, 0.f, 0.f, 0.f};
                acc0 = __builtin_amdgcn_mfma_f32_16x16x32_bf16(afrag[0], bf, acc0, 0, 0, 0);
                acc1 = __builtin_amdgcn_mfma_f32_16x16x32_bf16(afrag[1], bf, acc1, 0, 0, 0);

                bf16x8 h8;
                #pragma unroll
                for (int r = 0; r < 4; ++r) {
                    h8[r]     = (__bf16)fmaxf(acc0[r], 0.0f);
                    h8[4 + r] = (__bf16)fmaxf(acc1[r], 0.0f);
                }
                f32x4 o = {0.f, 0.f, 0.f, 0.f};
                o = __builtin_amdgcn_mfma_f32_16x16x32_bf16(a2, h8, o, 0, 0, 0);
                p[nt] = o[0];
            }

            float v = p[0];
            v = (g == 1) ? p[1] : v;
            v = (g == 2) ? p[2] : v;
            v = (g == 3) ? p[3] : v;
            out[(size_t)(tbase + t) * 64 + lane] = fmaxf(v + bias2, 0.0f);
        }
    }
}

extern "C" void kernel_launch(void* const* d_in, const int* in_sizes, int n_in,
                              void* d_out, int out_size, void* d_ws, size_t ws_size,
                              hipStream_t stream) {
    const float* x  = (const float*)d_in[0];
    const float* W1 = (const float*)d_in[1];
    const float* b1 = (const float*)d_in[2];
    const float* W2 = (const float*)d_in[3];
    const float* b2 = (const float*)d_in[4];
    float* out = (float*)d_out;

    nerf_mfma7_diag<<<NBLK, BLOCK, 0, stream>>>(x, W1, b1, W2, b2, out);
}

// Round 10
// 19.860 us; speedup vs baseline: 2.2304x; 2.2304x over previous
//
#include <hip/hip_runtime.h>

// Fused NeRF: PE (4 freq) + MLP 27->32->1, both layers bf16 MFMA (R7 struct).
// R9 change: ALL f32->bf16 conversions via __builtin_convertvector (emits
// v_cvt_pk_bf16_f32 pairs) instead of element-wise casts (which expand to
// multi-op round/shift + insert sequences). launch_bounds relaxed to (256,4).

#define NPTS  2097152
#define BLOCK 256
#define TILES 4
#define NBLK  (NPTS / (BLOCK * TILES))   // 2048

typedef __bf16 bf16x8 __attribute__((ext_vector_type(8)));
typedef float  f32x8  __attribute__((ext_vector_type(8)));
typedef float  f32x4  __attribute__((ext_vector_type(4)));

__global__ __launch_bounds__(BLOCK, 4) void nerf_mfma9(
    const float* __restrict__ x,
    const float* __restrict__ W1,
    const float* __restrict__ b1,
    const float* __restrict__ W2,
    const float* __restrict__ b2,
    float* __restrict__ out)
{
    const int tid  = threadIdx.x;
    const int wave = tid >> 6;
    const int lane = tid & 63;
    const int g    = lane >> 4;   // K-group: this lane's frequency band
    const int c    = lane & 15;   // col-within-16 (point low bits / j-row)

    const float INV2PI = 0.15915494309189535f;
    float Fg = 1.0f;
    Fg = (g == 1) ? 10.079368f : Fg;
    Fg = (g == 2) ? 101.59367f : Fg;
    Fg = (g == 3) ? 1024.0f    : Fg;
    Fg *= INV2PI;

    // ---- layer-1 A-fragments (W1 rows permuted to per-band k-order) ----
    // gathered as f32x8 then ONE vector convert (4x cvt_pk each)
    bf16x8 afrag[2];
    #pragma unroll
    for (int mt = 0; mt < 2; ++mt) {
        const int j = mt * 16 + c;
        f32x8 af;
        #pragma unroll
        for (int i = 0; i < 3; ++i)     af[i] = W1[(3 + 6 * g + i) * 32 + j];
        #pragma unroll
        for (int i = 3; i < 6; ++i)     af[i] = W1[(6 + 6 * g + (i - 3)) * 32 + j];
        af[6] = (g < 3) ? W1[g * 32 + j] : b1[j];
        af[7] = 0.0f;
        afrag[mt] = __builtin_convertvector(af, bf16x8);
    }

    // ---- layer-2 A-fragment: W2 by the same (g,i)->j rule ----
    bf16x8 a2;
    {
        f32x8 a2f;
        #pragma unroll
        for (int i = 0; i < 4; ++i) {
            a2f[i]     = W2[4 * g + i];
            a2f[4 + i] = W2[16 + 4 * g + i];
        }
        a2 = __builtin_convertvector(a2f, bf16x8);
    }
    const float bias2 = b2[0];

    const int tbase = blockIdx.x * (4 * TILES) + wave * TILES;

    #pragma unroll
    for (int t = 0; t < TILES; ++t) {
        const float3* xb3 = (const float3*)(x + (size_t)(tbase + t) * 192);
        float3 P[4];
        #pragma unroll
        for (int nt = 0; nt < 4; ++nt) P[nt] = xb3[16 * nt + c];

        float p[4];
        #pragma unroll
        for (int nt = 0; nt < 4; ++nt) {
            const float x0 = P[nt].x, x1 = P[nt].y, x2 = P[nt].z;

            const float a0  = __builtin_amdgcn_fractf(x0 * Fg);
            const float a1  = __builtin_amdgcn_fractf(x1 * Fg);
            const float a2r = __builtin_amdgcn_fractf(x2 * Fg);
            float extra = x0;
            extra = (g == 1) ? x1 : extra;
            extra = (g == 2) ? x2 : extra;
            extra = (g == 3) ? 1.0f : extra;

            f32x8 bff;
            bff[0] = __builtin_amdgcn_sinf(a0);
            bff[1] = __builtin_amdgcn_sinf(a1);
            bff[2] = __builtin_amdgcn_sinf(a2r);
            bff[3] = __builtin_amdgcn_cosf(a0);
            bff[4] = __builtin_amdgcn_cosf(a1);
            bff[5] = __builtin_amdgcn_cosf(a2r);
            bff[6] = extra;
            bff[7] = 0.0f;
            const bf16x8 bf = __builtin_convertvector(bff, bf16x8);

            // layer 1: 2 MFMAs -> lane holds h[4g+r] (acc0), h[16+4g+r] (acc1)
            f32x4 acc0 = {0.f, 0.f, 0.f, 0.f};
            f32x4 acc1 = {0.f, 0.f, 0.f, 0.f};
            acc0 = __builtin_amdgcn_mfma_f32_16x16x32_bf16(afrag[0], bf, acc0, 0, 0, 0);
            acc1 = __builtin_amdgcn_mfma_f32_16x16x32_bf16(afrag[1], bf, acc1, 0, 0, 0);

            // layer 2: relu in f32 (pk_max candidates), one vector convert
            f32x8 hf;
            #pragma unroll
            for (int r = 0; r < 4; ++r) {
                hf[r]     = fmaxf(acc0[r], 0.0f);
                hf[4 + r] = fmaxf(acc1[r], 0.0f);
            }
            const bf16x8 h8 = __builtin_convertvector(hf, bf16x8);
            f32x4 o = {0.f, 0.f, 0.f, 0.f};
            o = __builtin_amdgcn_mfma_f32_16x16x32_bf16(a2, h8, o, 0, 0, 0);
            p[nt] = o[0];   // lane's point answer (same across its D2 rows)
        }

        float v = p[0];
        v = (g == 1) ? p[1] : v;
        v = (g == 2) ? p[2] : v;
        v = (g == 3) ? p[3] : v;
        out[(size_t)(tbase + t) * 64 + lane] = fmaxf(v + bias2, 0.0f);
    }
}

extern "C" void kernel_launch(void* const* d_in, const int* in_sizes, int n_in,
                              void* d_out, int out_size, void* d_ws, size_t ws_size,
                              hipStream_t stream) {
    const float* x  = (const float*)d_in[0];
    const float* W1 = (const float*)d_in[1];
    const float* b1 = (const float*)d_in[2];
    const float* W2 = (const float*)d_in[3];
    const float* b2 = (const float*)d_in[4];
    float* out = (float*)d_out;

    nerf_mfma9<<<NBLK, BLOCK, 0, stream>>>(x, W1, b1, W2, b2, out);
}